// Round 2
// 1686.714 us; speedup vs baseline: 1.1604x; 1.1604x over previous
//
#include <hip/hip_runtime.h>
#include <stdint.h>

// Problem dims (TabM packed ensemble)
#define BB   4096
#define FF   512
#define HH   1024
#define CC   100
#define KE   32
#define NHIDL 3
#define CPAD 128   // W_out N padded to 128 (rows 100..127 zeroed)

typedef __attribute__((ext_vector_type(8))) short short8;   // 8 x fp16 = 4 VGPRs
typedef __attribute__((ext_vector_type(4))) float float4_t; // MFMA accumulator

// fp32 -> fp16 (RNE via hardware cvt)
__device__ __forceinline__ unsigned short f2h(float f) {
  _Float16 h = (_Float16)f;
  union { _Float16 h; unsigned short u; } cv;
  cv.h = h;
  return cv.u;
}

// async global->LDS, 16B per lane. LDS dest is wave-uniform base + lane*16.
__device__ __forceinline__ void gll16(const void* g, void* l) {
  __builtin_amdgcn_global_load_lds((const __attribute__((address_space(1))) void*)g,
                                   (__attribute__((address_space(3))) void*)l,
                                   16, 0, 0);
}

// ---------------------------------------------------------------------------
// elementwise fp32 -> fp16 convert (x)
__global__ void cvt_f16(const float* __restrict__ in, unsigned short* __restrict__ out, int n4) {
  int i = blockIdx.x * 256 + threadIdx.x;
  if (i < n4) {
    float4 v = ((const float4*)in)[i];
    ushort4 o;
    o.x = f2h(v.x); o.y = f2h(v.y); o.z = f2h(v.z); o.w = f2h(v.w);
    ((ushort4*)out)[i] = o;
  }
}

// ---------------------------------------------------------------------------
// batched transpose + convert: in fp32 [batch][R][C] -> out fp16 [batch][Cpad][R]
// (rows C..Cpad-1 of output zero-filled). R % 32 == 0 required.
__global__ void transpose_cvt(const float* __restrict__ in, unsigned short* __restrict__ out,
                              int R, int C, int Cpad) {
  __shared__ float tile[32][33];
  int b = blockIdx.z;
  const float* ib = in + (size_t)b * R * C;
  unsigned short* ob = out + (size_t)b * Cpad * R;
  int c0 = blockIdx.x * 32, r0 = blockIdx.y * 32;
  int tx = threadIdx.x & 31, ty = threadIdx.x >> 5;
#pragma unroll
  for (int j = 0; j < 4; ++j) {
    int r = r0 + ty + j * 8, c = c0 + tx;
    tile[ty + j * 8][tx] = (c < C) ? ib[(size_t)r * C + c] : 0.0f;
  }
  __syncthreads();
#pragma unroll
  for (int j = 0; j < 4; ++j) {
    int orow = c0 + ty + j * 8, ocol = r0 + tx;
    if (orow < Cpad) ob[(size_t)orow * R + ocol] = f2h(tile[tx][ty + j * 8]);
  }
}

// ---------------------------------------------------------------------------
// mean over ensemble: out[i] = (1/KE) * sum_k L[k*sk + i], i in [0, n)
__global__ void reduce_mean(const float* __restrict__ L, float* __restrict__ out,
                            int n, long long sk) {
  int i = blockIdx.x * 256 + threadIdx.x;
  if (i < n) {
    float s = 0.f;
#pragma unroll
    for (int k = 0; k < KE; ++k) s += L[(long long)k * sk + i];
    out[i] = s * (1.0f / (float)KE);
  }
}

// ---------------------------------------------------------------------------
// Old 128x128-tile GEMM (kept for the final layer, N=CPAD=128, and as fallback)
template <int RELU, int FINAL, int KD>
__global__ __launch_bounds__(256, 4) void gemm_f16(
    const unsigned short* __restrict__ A, long long sAk,
    const unsigned short* __restrict__ Bt, long long sBk,
    const float* __restrict__ bias, int sBiasK,
    unsigned short* __restrict__ Out, long long sOutK,
    float* __restrict__ OutF, long long sFk) {
  const int t = threadIdx.x;
  const int lane = t & 63;
  const int wave = t >> 6;
  const int wm = wave & 1;
  const int wn = wave >> 1;
  const int kz = blockIdx.z;
  const int m0 = blockIdx.y * 128;
  const int n0 = blockIdx.x * 128;

  const unsigned short* Ab = A + (long long)kz * sAk + (long long)m0 * KD;
  const unsigned short* Bb = Bt + (long long)kz * sBk + (long long)n0 * KD;

  __shared__ __align__(16) unsigned short smA[128 * 64];  // 16 KB
  __shared__ __align__(16) unsigned short smB[128 * 64];  // 16 KB

  float4_t acc[4][4];
#pragma unroll
  for (int i = 0; i < 4; ++i)
#pragma unroll
    for (int j = 0; j < 4; ++j) acc[i][j] = (float4_t){0.f, 0.f, 0.f, 0.f};

  int goff[4];
  unsigned short* la[4];
  unsigned short* lb[4];
#pragma unroll
  for (int j = 0; j < 4; ++j) {
    int s = j * 256 + t;
    int row = s >> 3;
    int g = (s & 7) ^ (row & 7);
    goff[j] = row * KD + g * 8;
    la[j] = smA + (size_t)((j * 256 + (t & 0xC0)) * 8);
    lb[j] = smB + (size_t)((j * 256 + (t & 0xC0)) * 8);
  }

  const int r16 = lane & 15;
  const int q = lane >> 4;
  int offA[4][2], offB[4][2];
#pragma unroll
  for (int i = 0; i < 4; ++i) {
#pragma unroll
    for (int kh = 0; kh < 2; ++kh) {
      int ra = wm * 64 + i * 16 + r16;
      offA[i][kh] = ra * 64 + ((((kh * 4 + q)) ^ (ra & 7)) << 3);
      int rb = wn * 64 + i * 16 + r16;
      offB[i][kh] = rb * 64 + ((((kh * 4 + q)) ^ (rb & 7)) << 3);
    }
  }

#pragma unroll
  for (int kt = 0; kt < KD; kt += 64) {
#pragma unroll
    for (int j = 0; j < 4; ++j) gll16(Ab + goff[j] + kt, la[j]);
#pragma unroll
    for (int j = 0; j < 4; ++j) gll16(Bb + goff[j] + kt, lb[j]);
    __syncthreads();

#pragma unroll
    for (int kh = 0; kh < 2; ++kh) {
      short8 af[4], bf[4];
#pragma unroll
      for (int i = 0; i < 4; ++i) af[i] = *(const short8*)(smA + offA[i][kh]);
#pragma unroll
      for (int i = 0; i < 4; ++i) bf[i] = *(const short8*)(smB + offB[i][kh]);
#pragma unroll
      for (int mi = 0; mi < 4; ++mi)
#pragma unroll
        for (int ni = 0; ni < 4; ++ni)
          acc[mi][ni] = __builtin_amdgcn_mfma_f32_16x16x32_f16(af[mi], bf[ni], acc[mi][ni], 0, 0, 0);
    }
    __syncthreads();
  }

  const int rbase = q * 4;
  if (FINAL) {
#pragma unroll
    for (int ni = 0; ni < 4; ++ni) {
      int n = wn * 64 + ni * 16 + r16;  // n0 == 0 for final layer
      if (n < CC) {
        float bv = bias[kz * sBiasK + n];
#pragma unroll
        for (int mi = 0; mi < 4; ++mi) {
#pragma unroll
          for (int r = 0; r < 4; ++r) {
            int m = m0 + wm * 64 + mi * 16 + rbase + r;
            OutF[(long long)kz * sFk + (long long)m * CC + n] = acc[mi][ni][r] + bv;
          }
        }
      }
    }
  } else {
#pragma unroll
    for (int ni = 0; ni < 4; ++ni) {
      int n = n0 + wn * 64 + ni * 16 + r16;
      float bv = bias[kz * sBiasK + n];
#pragma unroll
      for (int mi = 0; mi < 4; ++mi) {
        int m = m0 + wm * 64 + mi * 16 + rbase;
        unsigned short* op = Out + (long long)kz * sOutK + (long long)m * HH + n;
#pragma unroll
        for (int r = 0; r < 4; ++r) {
          float v = acc[mi][ni][r] + bv;
          if (RELU) v = fmaxf(v, 0.f);
          op[(long long)r * HH] = f2h(v);
        }
      }
    }
  }
}

// ---------------------------------------------------------------------------
// 256x256-tile, 8-phase counted-vmcnt GEMM (T1+T2+T3+T4+T5 schedule).
// 512 threads = 8 waves (2M x 4N); per-wave 128x64 output; BK=64; LDS 128 KiB
// double-buffered (buf = K-tile parity). Each K-tile = 4 quadrant phases
// (mh,nh) = (0,0),(0,1),(1,1),(1,0); each phase: {ds-read frags | 2x gll16
// prefetch} -> s_barrier -> lgkmcnt(0)+sched_barrier(0) -> setprio(1)
// 16xMFMA setprio(0) -> s_barrier. vmcnt(6) only at phases 4/8: retires
// exactly the 8 loads of the tile consumed next; 3 stage-pairs in flight
// across barriers. Stage ledger per iter j (E=2j buf0, O=2j+1 buf1,
// E'=E+2, O'=O+2):
//   P1:O.Aq13 P2:E'.Aq02 P3:E'.Bq01 P4:E'.Bq23+vm6 P5:E'.Aq13 P6:O'.Aq02
//   P7:O'.Bq01 P8:O'.Bq23+vm6
// Induction: entering iter j, 6 outstanding = O partial (Aq02,Bq01,Bq23);
// P4's vm6 retires those + P1's Aq13 = ALL of O before P5 reads it; P8's
// vm6 retires P2..P5's 8 = ALL of E' before next P1 reads it. Every stage
// lands >=1 closing barrier after the last ds_read of the region it
// overwrites (WAR-safe). LDS 16B-chunk swizzle: phys p holds logical
// p ^ (row&7) (proven scheme -> 0 bank conflicts).
template <int RELU, int KD>
__global__ __launch_bounds__(512, 2) void gemm256(
    const unsigned short* __restrict__ A, long long sAk,
    const unsigned short* __restrict__ Bt, long long sBk,
    const float* __restrict__ bias, int sBiasK,
    unsigned short* __restrict__ Out, long long sOutK) {
  static_assert(KD % 128 == 0, "need even K-tile count");
  const int t = threadIdx.x;
  const int lane = t & 63;
  const int wave = t >> 6;
  const int wm = wave >> 2;   // 0..1 (M half)
  const int wn = wave & 3;    // 0..3 (N quarter)
  const int r16 = lane & 15;
  const int q = lane >> 4;

  // XCD-aware bijective block swizzle (nwg % 8 == 0 by construction)
  const int gx = gridDim.x, gy = gridDim.y;
  const int gxy = gx * gy;
  const int nwg = gxy * gridDim.z;
  int flat = blockIdx.x + gx * (blockIdx.y + gy * blockIdx.z);
  int id2 = (flat & 7) * (nwg >> 3) + (flat >> 3);
  const int kz = id2 / gxy;
  int rem = id2 - kz * gxy;
  const int ty = rem / gx;
  const int tx = rem - ty * gx;
  const int m0 = ty * 256;
  const int n0 = tx * 256;

  const unsigned short* Ab = A + (long long)kz * sAk + (long long)m0 * KD;
  const unsigned short* Bb = Bt + (long long)kz * sBk + (long long)n0 * KD;

  __shared__ __align__(16) unsigned short sm[2 * 32768];  // [buf][A|B][16384] = 128 KB

  // staging: per gll16 issue, 512 threads cover one 64-row quarter (8 KB).
  // thread t -> row t>>3, phys chunk t&7 holding logical (t&7)^((t>>3)&7).
  const int gq = (t >> 3) * KD + ((((t & 7) ^ ((t >> 3) & 7))) << 3);  // element off
  const int wbase = wave * 512;  // shorts: wave-uniform LDS slot base in a quarter

  // fragment read addressing (row&7 == r16&7 for all frag rows)
  const int x7 = r16 & 7;
  const int xk0 = (q ^ x7) << 3;
  const int xk1 = ((4 + q) ^ x7) << 3;
  const int baseA = (wm * 128 + r16) * 64;
  const int baseB = (wn * 64 + r16) * 64;

  float4_t acc[8][4];
#pragma unroll
  for (int i = 0; i < 8; ++i)
#pragma unroll
    for (int j = 0; j < 4; ++j) acc[i][j] = (float4_t){0.f, 0.f, 0.f, 0.f};

  short8 af[4][2];  // current mh-half A frags
  short8 bf[4][2];  // all 4 ni B frags (nh0 pair + nh1 pair)

#define STGA(BUF, QI, TT) gll16(Ab + (QI) * 64 * KD + (TT) * 64 + gq, \
                                sm + (BUF) * 32768 + (QI) * 4096 + wbase)
#define STGB(BUF, QI, TT) gll16(Bb + (QI) * 64 * KD + (TT) * 64 + gq, \
                                sm + (BUF) * 32768 + 16384 + (QI) * 4096 + wbase)
#define DSA(BUF, MH) do { \
    const unsigned short* pA_ = sm + (BUF) * 32768 + baseA + (MH) * 4096; \
    _Pragma("unroll") for (int i_ = 0; i_ < 4; ++i_) { \
      af[i_][0] = *(const short8*)(pA_ + i_ * 1024 + xk0); \
      af[i_][1] = *(const short8*)(pA_ + i_ * 1024 + xk1); \
    } } while (0)
#define DSB(BUF, NH) do { \
    const unsigned short* pB_ = sm + (BUF) * 32768 + 16384 + baseB + (NH) * 2048; \
    _Pragma("unroll") for (int i_ = 0; i_ < 2; ++i_) { \
      bf[(NH) * 2 + i_][0] = *(const short8*)(pB_ + i_ * 1024 + xk0); \
      bf[(NH) * 2 + i_][1] = *(const short8*)(pB_ + i_ * 1024 + xk1); \
    } } while (0)
#define MM(MH, NH) do { \
    __builtin_amdgcn_s_setprio(1); \
    _Pragma("unroll") for (int mi_ = 0; mi_ < 4; ++mi_) { \
      _Pragma("unroll") for (int ni_ = 0; ni_ < 2; ++ni_) { \
        acc[(MH) * 4 + mi_][(NH) * 2 + ni_] = __builtin_amdgcn_mfma_f32_16x16x32_f16( \
            af[mi_][0], bf[(NH) * 2 + ni_][0], acc[(MH) * 4 + mi_][(NH) * 2 + ni_], 0, 0, 0); \
        acc[(MH) * 4 + mi_][(NH) * 2 + ni_] = __builtin_amdgcn_mfma_f32_16x16x32_f16( \
            af[mi_][1], bf[(NH) * 2 + ni_][1], acc[(MH) * 4 + mi_][(NH) * 2 + ni_], 0, 0, 0); \
      } } \
    __builtin_amdgcn_s_setprio(0); } while (0)
#define BAR() __builtin_amdgcn_s_barrier()
#define VMCNT(n) asm volatile("s_waitcnt vmcnt(" #n ")" ::: "memory")
// rule #18: fence register-only MFMA from hoisting above the wait
#define LGKM0() do { asm volatile("s_waitcnt lgkmcnt(0)" ::: "memory"); \
                     __builtin_amdgcn_sched_barrier(0); } while (0)

  // prologue: tile0 -> buf0 (8 loads, oldest), tile1 partial -> buf1 (6 loads)
  STGA(0, 0, 0); STGA(0, 1, 0); STGA(0, 2, 0); STGA(0, 3, 0);
  STGB(0, 0, 0); STGB(0, 1, 0); STGB(0, 2, 0); STGB(0, 3, 0);
  STGA(1, 0, 1); STGA(1, 2, 1);
  STGB(1, 0, 1); STGB(1, 1, 1); STGB(1, 2, 1); STGB(1, 3, 1);
  VMCNT(6);  // tile0 fully landed; tile1's 6 may be in flight
  BAR();

  const int nT = KD / 64;
  const int nI = nT / 2;
#pragma unroll 1
  for (int j = 0; j < nI - 1; ++j) {
    const int O1 = 2 * j + 1, E2 = 2 * j + 2, O2 = 2 * j + 3;
    // ---- K-tile E (buf0) ----
    DSA(0, 0); DSB(0, 0); STGA(1, 1, O1); STGA(1, 3, O1); BAR(); LGKM0(); MM(0, 0); BAR();
    DSB(0, 1);            STGA(0, 0, E2); STGA(0, 2, E2); BAR(); LGKM0(); MM(0, 1); BAR();
    DSA(0, 1);            STGB(0, 0, E2); STGB(0, 1, E2); BAR(); LGKM0(); MM(1, 1); BAR();
                          STGB(0, 2, E2); STGB(0, 3, E2); VMCNT(6); BAR(); MM(1, 0); BAR();
    // ---- K-tile O (buf1) ----
    DSA(1, 0); DSB(1, 0); STGA(0, 1, E2); STGA(0, 3, E2); BAR(); LGKM0(); MM(0, 0); BAR();
    DSB(1, 1);            STGA(1, 0, O2); STGA(1, 2, O2); BAR(); LGKM0(); MM(0, 1); BAR();
    DSA(1, 1);            STGB(1, 0, O2); STGB(1, 1, O2); BAR(); LGKM0(); MM(1, 1); BAR();
                          STGB(1, 2, O2); STGB(1, 3, O2); VMCNT(6); BAR(); MM(1, 0); BAR();
  }
  {  // peeled last iteration: only the carried O.Aq13 stage remains
    const int O1 = nT - 1;
    DSA(0, 0); DSB(0, 0); STGA(1, 1, O1); STGA(1, 3, O1); BAR(); LGKM0(); MM(0, 0); BAR();
    DSB(0, 1); BAR(); LGKM0(); MM(0, 1); BAR();
    DSA(0, 1); BAR(); LGKM0(); MM(1, 1); BAR();
    VMCNT(0); BAR(); MM(1, 0); BAR();  // drain: last tile fully in buf1
    DSA(1, 0); DSB(1, 0); BAR(); LGKM0(); MM(0, 0); BAR();
    DSB(1, 1); BAR(); LGKM0(); MM(0, 1); BAR();
    DSA(1, 1); LGKM0(); MM(1, 1); MM(1, 0);
  }

  // epilogue: C/D layout col = lane&15, row = (lane>>4)*4 + reg  [m89-verified]
  const int rbase = q * 4;
#pragma unroll
  for (int ni = 0; ni < 4; ++ni) {
    const int n = n0 + wn * 64 + ni * 16 + r16;
    const float bv = bias[kz * sBiasK + n];
#pragma unroll
    for (int mi = 0; mi < 8; ++mi) {
      const int m = m0 + wm * 128 + mi * 16 + rbase;
      unsigned short* op = Out + (long long)kz * sOutK + (long long)m * HH + n;
#pragma unroll
      for (int rr = 0; rr < 4; ++rr) {
        float v = acc[mi][ni][rr] + bv;
        if (RELU) v = fmaxf(v, 0.f);
        op[(long long)rr * HH] = f2h(v);
      }
    }
  }
#undef STGA
#undef STGB
#undef DSA
#undef DSB
#undef MM
#undef BAR
#undef VMCNT
#undef LGKM0
}

// ---------------------------------------------------------------------------
extern "C" void kernel_launch(void* const* d_in, const int* in_sizes, int n_in,
                              void* d_out, int out_size, void* d_ws, size_t ws_size,
                              hipStream_t stream) {
  (void)in_sizes; (void)n_in; (void)out_size;
  const float* x     = (const float*)d_in[0];
  const float* W_in  = (const float*)d_in[1];
  const float* b_in  = (const float*)d_in[2];
  const float* W_hid = (const float*)d_in[3];
  const float* b_hid = (const float*)d_in[4];
  const float* W_out = (const float*)d_in[5];
  const float* b_out = (const float*)d_in[6];
  float* out = (float*)d_out;

  char* ws = (char*)d_ws;
  size_t off = 0;
  auto alloc = [&](size_t bytes) -> void* {
    void* p = ws + off;
    off += (bytes + 255) & ~(size_t)255;
    return p;
  };
  unsigned short* xb    = (unsigned short*)alloc((size_t)BB * FF * 2);
  unsigned short* WinT  = (unsigned short*)alloc((size_t)KE * HH * FF * 2);
  unsigned short* WhidT = (unsigned short*)alloc((size_t)NHIDL * KE * HH * HH * 2);
  unsigned short* WoutT = (unsigned short*)alloc((size_t)KE * CPAD * HH * 2);
  size_t fixed = off;

  int Bc = BB;  // batch chunk; shrink if workspace is small
  while (Bc > 128 && fixed + 2 * (size_t)KE * Bc * HH * 2 > ws_size) Bc >>= 1;
  unsigned short* h0 = (unsigned short*)alloc((size_t)KE * Bc * HH * 2);
  unsigned short* h1 = (unsigned short*)alloc((size_t)KE * Bc * HH * 2);

  // conversions / weight transposes (fp32 -> fp16, W stored N-major)
  cvt_f16<<<(BB * FF / 4 + 255) / 256, 256, 0, stream>>>(x, xb, BB * FF / 4);
  transpose_cvt<<<dim3(HH / 32, FF / 32, KE), 256, 0, stream>>>(W_in, WinT, FF, HH, HH);
  transpose_cvt<<<dim3(HH / 32, HH / 32, NHIDL * KE), 256, 0, stream>>>(W_hid, WhidT, HH, HH, HH);
  transpose_cvt<<<dim3(CPAD / 32, HH / 32, KE), 256, 0, stream>>>(W_out, WoutT, HH, CC, CPAD);

  const bool big = (Bc % 256) == 0;  // 256-tile path needs Bc multiple of 256

  for (int c0 = 0; c0 < BB; c0 += Bc) {
    // layer 0: [Bc,F] @ [F,H] (A shared across k -> stride 0)
    if (big) {
      gemm256<1, FF><<<dim3(HH / 256, Bc / 256, KE), 512, 0, stream>>>(
          xb + (size_t)c0 * FF, 0LL, WinT, (long long)HH * FF, b_in, HH,
          h0, (long long)Bc * HH);
    } else {
      gemm_f16<1, 0, FF><<<dim3(HH / 128, Bc / 128, KE), 256, 0, stream>>>(
          xb + (size_t)c0 * FF, 0LL, WinT, (long long)HH * FF, b_in, HH,
          h0, (long long)Bc * HH, nullptr, 0LL);
    }
    unsigned short* hin = h0;
    unsigned short* hout = h1;
    for (int l = 0; l < NHIDL; ++l) {
      if (big) {
        gemm256<1, HH><<<dim3(HH / 256, Bc / 256, KE), 512, 0, stream>>>(
            hin, (long long)Bc * HH, WhidT + (size_t)l * KE * HH * HH, (long long)HH * HH,
            b_hid + (size_t)l * KE * HH, HH, hout, (long long)Bc * HH);
      } else {
        gemm_f16<1, 0, HH><<<dim3(HH / 128, Bc / 128, KE), 256, 0, stream>>>(
            hin, (long long)Bc * HH, WhidT + (size_t)l * KE * HH * HH, (long long)HH * HH,
            b_hid + (size_t)l * KE * HH, HH, hout, (long long)Bc * HH, nullptr, 0LL);
      }
      unsigned short* tmp = hin; hin = hout; hout = tmp;
    }
    // output layer: per-k fp32 logits into the dead h-buffer (hout), then mean
    float* Lbuf = (float*)hout;  // KE*Bc*CC*4 <= KE*Bc*HH*2 always
    gemm_f16<0, 1, HH><<<dim3(1, Bc / 128, KE), 256, 0, stream>>>(
        hin, (long long)Bc * HH, WoutT, (long long)CPAD * HH, b_out, CC,
        nullptr, 0LL, Lbuf, (long long)Bc * CC);
    reduce_mean<<<(Bc * CC + 255) / 256, 256, 0, stream>>>(
        Lbuf, out + (size_t)c0 * CC, Bc * CC, (long long)Bc * CC);
  }
}